// Round 11
// baseline (1466.270 us; speedup 1.0000x reference)
//
#include <hip/hip_runtime.h>

// Problem constants (fixed by setup_inputs)
constexpr int B   = 16;
constexpr int N   = 16384;
constexpr int M   = 256;   // n_centers
constexpr int K   = 32;    // knn
constexpr int EMB = 256;

// Exact (non-contracted) squared distance in the reference's association
// order: ((dx*dx + dy*dy) + dz*dz). Must be bit-identical to XLA CPU so the
// FPS argmax / kNN top-k selections match.
__device__ __forceinline__ float sqdist(float px, float py, float pz,
                                        float cx, float cy, float cz) {
  float dx = __fsub_rn(px, cx);
  float dy = __fsub_rn(py, cy);
  float dz = __fsub_rn(pz, cz);
  return __fadd_rn(__fadd_rn(__fmul_rn(dx, dx), __fmul_rn(dy, dy)),
                   __fmul_rn(dz, dz));
}

// ---------------------------------------------------------------- FPS ------
// History: r5-r10 single-block-per-batch designs all failed the same way:
// the allocator refuses to hold >~40 long-lived floats/thread (VGPR grants
// 40-88 across every hint combo), spilling state to scratch/L1 -> 577-793us.
// v4 design: 8 blocks/batch x 256 thr, 8 pts/thread -> 32 named floats of
// state (allocator-proof). Per-iteration global argmax via cross-block
// all-to-all handshake in d_ws: release-publish {val,idx,coords,seq},
// acquire-poll all 8 records (device-scope atomics), butterfly reduce with
// (val desc, idx asc) total order -> deterministic, bit-identical result.
// An init kernel zeroes seq each launch (stream-ordered; graph-replay-safe).
// All 128 blocks are trivially co-resident (<< 256 CUs) so spinning is safe.
constexpr int FBLK = 8;            // sub-blocks per batch
constexpr int FTH  = 256;          // threads per fps block
constexpr int FPTS = N / FBLK;     // 2048 points per block
constexpr int FPT  = FPTS / FTH;   // 8 points per thread
constexpr int RECI = 8;            // ints per record (32 B)
constexpr size_t PATCH_FLOATS = (size_t)B * M * K * 3;

#define FPS_REP8(X) X(0) X(1) X(2) X(3) X(4) X(5) X(6) X(7)

__global__ __launch_bounds__(256) void fps_init_kernel(int* __restrict__ sync) {
  // zero all B*FBLK records (seq fields included)
  const int tot = B * FBLK * RECI;           // 1024 ints
  for (int i = threadIdx.x; i < tot; i += 256) sync[i] = 0;
}

__global__ __launch_bounds__(FTH, 2) void fps_kernel(
    const float* __restrict__ xyz, float* __restrict__ centers,
    int* __restrict__ sync) {
  const int gb = blockIdx.x;        // 0..127
  const int b  = gb >> 3;           // batch
  const int sb = gb & 7;            // sub-block within batch
  const int tid = threadIdx.x;
  const float* base = xyz + (size_t)b * N * 3;
  const int pbase = sb * FPTS;      // first point this block owns
  int* recs  = sync + (size_t)b * (FBLK * RECI);
  int* myrec = recs + sb * RECI;

  // 8 points/thread in named scalars: 24 coords + 8 dists = 32 floats.
#define FPS_DECL(i) float x##i, y##i, z##i, d##i;
  FPS_REP8(FPS_DECL)
#undef FPS_DECL
#define FPS_LOAD(i) { const int n = pbase + tid + (i) * FTH; \
    x##i = base[n * 3 + 0];                                   \
    y##i = base[n * 3 + 1];                                   \
    z##i = base[n * 3 + 2];                                   \
    d##i = __builtin_inff(); }
  FPS_REP8(FPS_LOAD)
#undef FPS_LOAD

  __shared__ float s_pv[FTH / 64];
  __shared__ int s_pn[FTH / 64];
  __shared__ float s_c[3];

  // deterministic start: carry = point 0 of the batch
  float cx = base[0], cy = base[1], cz = base[2];

  for (int it = 0; it < M; ++it) {
    if (sb == 0 && tid == 0) {  // emit current carry (lax.scan semantics)
      float* co = centers + ((size_t)b * M + it) * 3;
      co[0] = cx; co[1] = cy; co[2] = cz;
    }

    // local update; track per-thread max (value, local j), strict > so the
    // lowest local index (and thus lowest global index) wins ties.
    float bv = -1.0f;
    int bj = 0;
#define FPS_UPD(i) {                                          \
    float ddx = __fsub_rn(x##i, cx);                          \
    float ddy = __fsub_rn(y##i, cy);                          \
    float ddz = __fsub_rn(z##i, cz);                          \
    float dd = __fadd_rn(__fadd_rn(__fmul_rn(ddx, ddx),       \
                                   __fmul_rn(ddy, ddy)),      \
                         __fmul_rn(ddz, ddz));                \
    float nd = fminf(d##i, dd);                               \
    d##i = nd;                                                \
    bool g = nd > bv;                                         \
    bv = g ? nd : bv;                                         \
    bj = g ? (i) : bj; }
    FPS_REP8(FPS_UPD)
#undef FPS_UPD
    int bn = pbase + (bj << 8) + tid;   // global point index (FTH == 256)

    // wave-level argmax, tie -> lowest global index
#pragma unroll
    for (int mm = 32; mm >= 1; mm >>= 1) {
      float ov = __shfl_xor(bv, mm, 64);
      int on = __shfl_xor(bn, mm, 64);
      if (ov > bv || (ov == bv && on < bn)) { bv = ov; bn = on; }
    }
    if ((tid & 63) == 0) { s_pv[tid >> 6] = bv; s_pn[tid >> 6] = bn; }
    __syncthreads();                    // barrier 1

    // block-best from the 4 wave partials (every thread, broadcast reads)
    float v = s_pv[0];
    int n = s_pn[0];
#pragma unroll
    for (int w = 1; w < FTH / 64; ++w) {
      float ov = s_pv[w];
      int on = s_pn[w];
      if (ov > v || (ov == v && on < n)) { v = ov; n = on; }
    }

    // owner thread publishes the block record (payload relaxed, seq release)
    const int loc = n - pbase;
    if (tid == (loc & 255)) {
      const int j = loc >> 8;
      float wx = x0, wy = y0, wz = z0;
      if (j == 1) { wx = x1; wy = y1; wz = z1; }
      if (j == 2) { wx = x2; wy = y2; wz = z2; }
      if (j == 3) { wx = x3; wy = y3; wz = z3; }
      if (j == 4) { wx = x4; wy = y4; wz = z4; }
      if (j == 5) { wx = x5; wy = y5; wz = z5; }
      if (j == 6) { wx = x6; wy = y6; wz = z6; }
      if (j == 7) { wx = x7; wy = y7; wz = z7; }
      __hip_atomic_store(myrec + 0, __float_as_int(v), __ATOMIC_RELAXED,
                         __HIP_MEMORY_SCOPE_AGENT);
      __hip_atomic_store(myrec + 1, n, __ATOMIC_RELAXED,
                         __HIP_MEMORY_SCOPE_AGENT);
      __hip_atomic_store(myrec + 2, __float_as_int(wx), __ATOMIC_RELAXED,
                         __HIP_MEMORY_SCOPE_AGENT);
      __hip_atomic_store(myrec + 3, __float_as_int(wy), __ATOMIC_RELAXED,
                         __HIP_MEMORY_SCOPE_AGENT);
      __hip_atomic_store(myrec + 4, __float_as_int(wz), __ATOMIC_RELAXED,
                         __HIP_MEMORY_SCOPE_AGENT);
      __hip_atomic_store(myrec + 5, it + 1, __ATOMIC_RELEASE,
                         __HIP_MEMORY_SCOPE_AGENT);
    }

    // wave 0 lanes 0..7: poll all 8 records, butterfly to global winner
    if (tid < FBLK) {
      int* r = recs + tid * RECI;
      while (__hip_atomic_load(r + 5, __ATOMIC_ACQUIRE,
                               __HIP_MEMORY_SCOPE_AGENT) < it + 1) {}
      float rv = __int_as_float(__hip_atomic_load(r + 0, __ATOMIC_RELAXED,
                                                  __HIP_MEMORY_SCOPE_AGENT));
      int rn = __hip_atomic_load(r + 1, __ATOMIC_RELAXED,
                                 __HIP_MEMORY_SCOPE_AGENT);
      float rcx = __int_as_float(__hip_atomic_load(r + 2, __ATOMIC_RELAXED,
                                                   __HIP_MEMORY_SCOPE_AGENT));
      float rcy = __int_as_float(__hip_atomic_load(r + 3, __ATOMIC_RELAXED,
                                                   __HIP_MEMORY_SCOPE_AGENT));
      float rcz = __int_as_float(__hip_atomic_load(r + 4, __ATOMIC_RELAXED,
                                                   __HIP_MEMORY_SCOPE_AGENT));
      float v2 = rv;
      int n2 = rn;
#pragma unroll
      for (int m2 = 1; m2 <= 4; m2 <<= 1) {
        float ov = __shfl_xor(v2, m2, 8);
        int on = __shfl_xor(n2, m2, 8);
        if (ov > v2 || (ov == v2 && on < n2)) { v2 = ov; n2 = on; }
      }
      if (rn == n2) { s_c[0] = rcx; s_c[1] = rcy; s_c[2] = rcz; }  // unique
    }
    __syncthreads();                    // barrier 2
    cx = s_c[0]; cy = s_c[1]; cz = s_c[2];
  }
}

// ---------------------------------------------------------------- kNN ------
// Bucket-select on float bit prefixes (monotone for d >= 0). Only the SET of
// 32 nearest matters (max-pool later), so slots are written in arbitrary
// order; boundary-bucket ties resolved exactly by (bits, index).
constexpr int KT = 256;
constexpr int CAP = 512;
constexpr int NBUCKET = 1024;

__global__ __launch_bounds__(KT) void knn_kernel(
    const float* __restrict__ xyz, const float* __restrict__ centers,
    float* __restrict__ patches) {
  const int blk = blockIdx.x;      // b*M + m
  const int b = blk >> 8;          // M == 256
  const int tid = threadIdx.x;
  const float* base = xyz + (size_t)b * N * 3;

  __shared__ int hist[NBUCKET];
  __shared__ unsigned cb[CAP];
  __shared__ int ci[CAP];
  __shared__ int s_nin, s_ncand, s_tb;
  __shared__ int s_wsum[KT / 64];
  __shared__ float s_cc[3];

  if (tid == 0) {
    const float* c = centers + (size_t)blk * 3;
    s_cc[0] = c[0]; s_cc[1] = c[1]; s_cc[2] = c[2];
    s_nin = 0; s_ncand = 0;
  }
  for (int i = tid; i < NBUCKET; i += KT) hist[i] = 0;
  __syncthreads();

  const float cx = s_cc[0], cy = s_cc[1], cz = s_cc[2];

  // pass 1: histogram of 10-bit float prefixes
  for (int n = tid; n < N; n += KT) {
    float d = sqdist(base[n * 3], base[n * 3 + 1], base[n * 3 + 2], cx, cy, cz);
    atomicAdd(&hist[__float_as_uint(d) >> 21], 1);
  }
  __syncthreads();

  // block scan over 1024 buckets (4 per thread) to find threshold bucket
  int h0[4];
  int loc = 0;
#pragma unroll
  for (int i = 0; i < 4; ++i) { h0[i] = hist[tid * 4 + i]; loc += h0[i]; }
  int lane = tid & 63, wid = tid >> 6;
  int scan = loc;
  for (int off = 1; off < 64; off <<= 1) {
    int o = __shfl_up(scan, off, 64);
    if (lane >= off) scan += o;
  }
  if (lane == 63) s_wsum[wid] = scan;
  __syncthreads();
  int woff = 0;
  for (int w = 0; w < wid; ++w) woff += s_wsum[w];
  int c0 = woff + scan - loc;  // count strictly below this thread's buckets
#pragma unroll
  for (int i = 0; i < 4; ++i) {
    int c1 = c0 + h0[i];
    if (c0 < K && c1 >= K) s_tb = tid * 4 + i;  // unique crossing bucket
    c0 = c1;
  }
  __syncthreads();
  const int tb = s_tb;
  const unsigned lo = (unsigned)tb << 21;
  const unsigned hi = (unsigned)(tb + 1) << 21;

  // pass 2: emit sure-ins, collect boundary candidates
  for (int n = tid; n < N; n += KT) {
    float x = base[n * 3], y = base[n * 3 + 1], z = base[n * 3 + 2];
    float d = sqdist(x, y, z, cx, cy, cz);
    unsigned bits = __float_as_uint(d);
    if (bits < lo) {
      int pos = atomicAdd(&s_nin, 1);
      float* p = patches + ((size_t)blk * K + pos) * 3;
      p[0] = __fsub_rn(x, cx); p[1] = __fsub_rn(y, cy); p[2] = __fsub_rn(z, cz);
    } else if (bits < hi) {
      int q = atomicAdd(&s_ncand, 1);
      if (q < CAP) { cb[q] = bits; ci[q] = n; }
    }
  }
  __syncthreads();

  // exact rank-select among boundary candidates: (bits, idx) lexicographic
  const int nin = s_nin;
  const int ncand = min(s_ncand, CAP);
  const int nsel = K - nin;
  for (int j = tid; j < ncand; j += KT) {
    unsigned bj = cb[j];
    int ij = ci[j];
    int rank = 0;
    for (int i2 = 0; i2 < ncand; ++i2) {
      unsigned bv = cb[i2];
      int iv = ci[i2];
      rank += (bv < bj || (bv == bj && iv < ij)) ? 1 : 0;
    }
    if (rank < nsel) {
      float x = base[ij * 3], y = base[ij * 3 + 1], z = base[ij * 3 + 2];
      float* p = patches + ((size_t)blk * K + nin + rank) * 3;
      p[0] = __fsub_rn(x, cx); p[1] = __fsub_rn(y, cy); p[2] = __fsub_rn(z, cz);
    }
  }
}

// ---------------------------------------------------------------- MLP ------
// One block per patch. h1/h2 staged in LDS, rows XOR-swizzled so the b128
// writes are conflict-light; reads are uniform-address broadcasts.
constexpr int MT = 128;

__global__ __launch_bounds__(MT) void mlp_kernel(
    const float* __restrict__ patches,
    const float* __restrict__ W1, const float* __restrict__ b1,
    const float* __restrict__ g1, const float* __restrict__ bt1,
    const float* __restrict__ W2, const float* __restrict__ b2,
    const float* __restrict__ g2, const float* __restrict__ bt2,
    const float* __restrict__ W3, const float* __restrict__ b3,
    const float* __restrict__ g3, const float* __restrict__ bt3,
    float* __restrict__ tokens) {
  const int pm = blockIdx.x;
  const int tid = threadIdx.x;
  __shared__ float xs[3][K];
  __shared__ float h1s[64 * K];
  __shared__ float h2s[128 * K];
  __shared__ float pms[2][EMB];

  const float* patch = patches + (size_t)pm * (K * 3);
  if (tid < 96) xs[tid % 3][tid / 3] = patch[tid];
  __syncthreads();

  const int cg = tid & 63;
  const int half = tid >> 6;
  const int pt0 = half * 16;
  const float rs = 1.0f / sqrtf(1.0f + 1e-5f);

  // L1: 3 -> 64
  {
    const int c = cg;
    const float w0 = W1[c], w1 = W1[64 + c], w2 = W1[128 + c];
    const float bb = b1[c];
    const float sc = g1[c] * rs, be = bt1[c];
    float o[16];
#pragma unroll
    for (int p = 0; p < 16; ++p) {
      int pt = pt0 + p;
      float a = xs[0][pt] * w0 + xs[1][pt] * w1 + xs[2][pt] * w2 + bb;
      o[p] = fmaxf(a * sc + be, 0.0f);
    }
    const int so = (c & 7) << 2;
#pragma unroll
    for (int p4 = 0; p4 < 16; p4 += 4) {
      *(float4*)&h1s[c * K + ((pt0 + p4) ^ so)] =
          make_float4(o[p4], o[p4 + 1], o[p4 + 2], o[p4 + 3]);
    }
  }
  __syncthreads();

  // L2: 64 -> 128, c-tile 2 x pt-tile 16
  {
    const int c = cg * 2;
    float acc0[16], acc1[16];
    const float bb0 = b2[c], bb1 = b2[c + 1];
#pragma unroll
    for (int p = 0; p < 16; ++p) { acc0[p] = bb0; acc1[p] = bb1; }
    for (int k = 0; k < 64; ++k) {
      const float2 w = *(const float2*)(W2 + k * 128 + c);
      const int so = (k & 7) << 2;
      float4 x0 = *(const float4*)&h1s[k * K + ((pt0 + 0) ^ so)];
      float4 x1 = *(const float4*)&h1s[k * K + ((pt0 + 4) ^ so)];
      float4 x2 = *(const float4*)&h1s[k * K + ((pt0 + 8) ^ so)];
      float4 x3 = *(const float4*)&h1s[k * K + ((pt0 + 12) ^ so)];
      float xv[16] = {x0.x, x0.y, x0.z, x0.w, x1.x, x1.y, x1.z, x1.w,
                      x2.x, x2.y, x2.z, x2.w, x3.x, x3.y, x3.z, x3.w};
#pragma unroll
      for (int p = 0; p < 16; ++p) {
        acc0[p] += xv[p] * w.x;
        acc1[p] += xv[p] * w.y;
      }
    }
    const float sc0 = g2[c] * rs, be0 = bt2[c];
    const float sc1 = g2[c + 1] * rs, be1 = bt2[c + 1];
    float o0[16], o1[16];
#pragma unroll
    for (int p = 0; p < 16; ++p) {
      o0[p] = fmaxf(acc0[p] * sc0 + be0, 0.0f);
      o1[p] = fmaxf(acc1[p] * sc1 + be1, 0.0f);
    }
    const int soa = (c & 7) << 2, sob = ((c + 1) & 7) << 2;
#pragma unroll
    for (int p4 = 0; p4 < 16; p4 += 4) {
      *(float4*)&h2s[c * K + ((pt0 + p4) ^ soa)] =
          make_float4(o0[p4], o0[p4 + 1], o0[p4 + 2], o0[p4 + 3]);
      *(float4*)&h2s[(c + 1) * K + ((pt0 + p4) ^ sob)] =
          make_float4(o1[p4], o1[p4 + 1], o1[p4 + 2], o1[p4 + 3]);
    }
  }
  __syncthreads();

  // L3: 128 -> 256, c-tile 4 x pt-tile 16, fused BN+ReLU+max over its pts
  {
    const int c = cg * 4;
    float acc[4][16];
#pragma unroll
    for (int i = 0; i < 4; ++i) {
      const float bb = b3[c + i];
#pragma unroll
      for (int p = 0; p < 16; ++p) acc[i][p] = bb;
    }
    for (int k = 0; k < 128; ++k) {
      const float4 w = *(const float4*)(W3 + (size_t)k * 256 + c);
      const int so = (k & 7) << 2;
      float4 x0 = *(const float4*)&h2s[k * K + ((pt0 + 0) ^ so)];
      float4 x1 = *(const float4*)&h2s[k * K + ((pt0 + 4) ^ so)];
      float4 x2 = *(const float4*)&h2s[k * K + ((pt0 + 8) ^ so)];
      float4 x3 = *(const float4*)&h2s[k * K + ((pt0 + 12) ^ so)];
      float xv[16] = {x0.x, x0.y, x0.z, x0.w, x1.x, x1.y, x1.z, x1.w,
                      x2.x, x2.y, x2.z, x2.w, x3.x, x3.y, x3.z, x3.w};
#pragma unroll
      for (int p = 0; p < 16; ++p) {
        acc[0][p] += xv[p] * w.x;
        acc[1][p] += xv[p] * w.y;
        acc[2][p] += xv[p] * w.z;
        acc[3][p] += xv[p] * w.w;
      }
    }
#pragma unroll
    for (int i = 0; i < 4; ++i) {
      const float sc = g3[c + i] * rs, be = bt3[c + i];
      float mx = 0.0f;  // ReLU outputs are >= 0, so 0 is a safe identity
#pragma unroll
      for (int p = 0; p < 16; ++p)
        mx = fmaxf(mx, fmaxf(acc[i][p] * sc + be, 0.0f));
      pms[half][c + i] = mx;
    }
  }
  __syncthreads();

  {
    const int c2 = tid * 2;
    float* to = tokens + (size_t)pm * EMB;
    to[c2] = fmaxf(pms[0][c2], pms[1][c2]);
    to[c2 + 1] = fmaxf(pms[0][c2 + 1], pms[1][c2 + 1]);
  }
}

// ------------------------------------------------------------- launcher ----
extern "C" void kernel_launch(void* const* d_in, const int* in_sizes, int n_in,
                              void* d_out, int out_size, void* d_ws,
                              size_t ws_size, hipStream_t stream) {
  const float* xyz = (const float*)d_in[0];
  const float* W1 = (const float*)d_in[1];
  const float* b1 = (const float*)d_in[2];
  const float* g1 = (const float*)d_in[3];
  const float* bt1 = (const float*)d_in[4];
  const float* W2 = (const float*)d_in[5];
  const float* b2 = (const float*)d_in[6];
  const float* g2 = (const float*)d_in[7];
  const float* bt2 = (const float*)d_in[8];
  const float* W3 = (const float*)d_in[9];
  const float* b3 = (const float*)d_in[10];
  const float* g3 = (const float*)d_in[11];
  const float* bt3 = (const float*)d_in[12];

  float* tokens = (float*)d_out;                       // (B,M,EMB)
  float* centers = tokens + (size_t)B * M * EMB;       // (B,M,3)
  float* patches = (float*)d_ws;                       // (B*M, K, 3)
  int* sync = (int*)((char*)d_ws + PATCH_FLOATS * sizeof(float));

  fps_init_kernel<<<1, 256, 0, stream>>>(sync);
  fps_kernel<<<B * FBLK, FTH, 0, stream>>>(xyz, centers, sync);
  knn_kernel<<<B * M, KT, 0, stream>>>(xyz, centers, patches);
  mlp_kernel<<<B * M, MT, 0, stream>>>(patches, W1, b1, g1, bt1, W2, b2, g2,
                                       bt2, W3, b3, g3, bt3, tokens);
}

// Round 12
// 1013.133 us; speedup vs baseline: 1.4473x; 1.4473x over previous
//
#include <hip/hip_runtime.h>

// Problem constants (fixed by setup_inputs)
constexpr int B   = 16;
constexpr int N   = 16384;
constexpr int M   = 256;   // n_centers
constexpr int K   = 32;    // knn
constexpr int EMB = 256;

// Exact (non-contracted) squared distance in the reference's association
// order: ((dx*dx + dy*dy) + dz*dz). Must be bit-identical to XLA CPU so the
// FPS argmax / kNN top-k selections match.
__device__ __forceinline__ float sqdist(float px, float py, float pz,
                                        float cx, float cy, float cz) {
  float dx = __fsub_rn(px, cx);
  float dy = __fsub_rn(py, cy);
  float dz = __fsub_rn(pz, cz);
  return __fadd_rn(__fadd_rn(__fmul_rn(dx, dx), __fmul_rn(dy, dy)),
                   __fmul_rn(dz, dz));
}

// ---------------------------------------------------------------- FPS ------
// r5-r11 lesson: the allocator spills ANY >~32-float per-thread state
// (VGPR grants 36-88 across every hint), and cross-block sync costs
// ~4.5us/iter. So: single block/batch, ALL bulk state in explicitly-managed
// memory, exploiting that LDS (128B/cyc) and vector-memory (~60B/cyc) are
// separate overlapping pipes:
//   - dist[16384] in LDS (64KB)           - RMW 128KB/iter on LDS pipe
//   - coords of 7168 pts in LDS SoA (84KB)- 84KB/iter on LDS pipe
//   - coords of 9216 pts streamed from L1/L2 (108KB/iter on VMEM pipe)
// gfx950 addressable LDS = 160KB, so 148KB static is legal.
// ~1850cyc/iter memory + ~500cyc tail ~= 1.3us/iter.
constexpr int FT = 1024;          // threads
constexpr int LPT = 7;            // LDS-resident points per thread
constexpr int SPT = 9;            // streamed points per thread (7+9=16)
constexpr int FW = FT / 64;       // 16 waves

__global__ __launch_bounds__(FT) void fps_kernel(
    const float* __restrict__ xyz, float* __restrict__ centers) {
  const int b = blockIdx.x;
  const int tid = threadIdx.x;
  const float* base = xyz + (size_t)b * N * 3;

  __shared__ float s_dist[N];           // 64 KB
  __shared__ float s_cx[LPT * FT];      // 28 KB
  __shared__ float s_cy[LPT * FT];      // 28 KB
  __shared__ float s_cz[LPT * FT];      // 28 KB
  __shared__ float s_pv[2][FW];
  __shared__ int s_pn[2][FW];

  // stage: LDS-resident coords (pts n = i*1024+tid, i<7); dist = +inf
#pragma unroll
  for (int i = 0; i < LPT; ++i) {
    const int n = i * FT + tid;
    s_cx[n] = base[n * 3 + 0];
    s_cy[n] = base[n * 3 + 1];
    s_cz[n] = base[n * 3 + 2];
  }
#pragma unroll
  for (int i = 0; i < 16; ++i) s_dist[i * FT + tid] = __builtin_inff();

  // deterministic start: carry = point 0
  float cx = base[0], cy = base[1], cz = base[2];
  __syncthreads();

  for (int it = 0; it < M; ++it) {
    if (tid == 0) {  // emit current carry (matches lax.scan semantics)
      float* co = centers + ((size_t)b * M + it) * 3;
      co[0] = cx; co[1] = cy; co[2] = cz;
    }
    const int p = it & 1;

    float bv = -1.0f;
    int bj = 0;

    // streamed points (i = 7..15): global loads issue first, latency hides
    // under the LDS-point processing below.
    float gx[SPT], gy[SPT], gz[SPT];
#pragma unroll
    for (int i = 0; i < SPT; ++i) {
      const int n = (LPT + i) * FT + tid;
      gx[i] = base[n * 3 + 0];
      gy[i] = base[n * 3 + 1];
      gz[i] = base[n * 3 + 2];
    }

    // LDS-resident points (i = 0..6)
#pragma unroll
    for (int i = 0; i < LPT; ++i) {
      const int n = i * FT + tid;
      float d = sqdist(s_cx[n], s_cy[n], s_cz[n], cx, cy, cz);
      float od = s_dist[n];
      float nd = fminf(od, d);
      s_dist[n] = nd;
      bool g = nd > bv;          // strict > : lowest i wins ties
      bv = g ? nd : bv;
      bj = g ? i : bj;
    }
#pragma unroll
    for (int i = 0; i < SPT; ++i) {
      const int n = (LPT + i) * FT + tid;
      float d = sqdist(gx[i], gy[i], gz[i], cx, cy, cz);
      float od = s_dist[n];
      float nd = fminf(od, d);
      s_dist[n] = nd;
      bool g = nd > bv;
      bv = g ? nd : bv;
      bj = g ? (LPT + i) : bj;
    }
    int bn = (bj << 10) + tid;   // global point index (FT == 1024)

    // wave-level argmax, tie -> lowest global index
#pragma unroll
    for (int mm = 32; mm >= 1; mm >>= 1) {
      float ov = __shfl_xor(bv, mm, 64);
      int on = __shfl_xor(bn, mm, 64);
      if (ov > bv || (ov == bv && on < bn)) { bv = ov; bn = on; }
    }
    if ((tid & 63) == 0) { s_pv[p][tid >> 6] = bv; s_pn[p][tid >> 6] = bn; }
    __syncthreads();

    // every thread reduces the 16 wave partials (broadcast LDS reads)
    float v = s_pv[p][0];
    int n = s_pn[p][0];
#pragma unroll
    for (int w = 1; w < FW; ++w) {
      float ov = s_pv[p][w];
      int on = s_pn[p][w];
      if (ov > v || (ov == v && on < n)) { v = ov; n = on; }
    }
    // broadcast-load next center (uniform address -> one L1 fetch)
    cx = base[(size_t)n * 3 + 0];
    cy = base[(size_t)n * 3 + 1];
    cz = base[(size_t)n * 3 + 2];
    // no second barrier: parity-double-buffered partials make it race-free
  }
}

// ---------------------------------------------------------------- kNN ------
// Bucket-select on float bit prefixes (monotone for d >= 0). Only the SET of
// 32 nearest matters (max-pool later), so slots are written in arbitrary
// order; boundary-bucket ties resolved exactly by (bits, index).
constexpr int KT = 256;
constexpr int CAP = 512;
constexpr int NBUCKET = 1024;

__global__ __launch_bounds__(KT) void knn_kernel(
    const float* __restrict__ xyz, const float* __restrict__ centers,
    float* __restrict__ patches) {
  const int blk = blockIdx.x;      // b*M + m
  const int b = blk >> 8;          // M == 256
  const int tid = threadIdx.x;
  const float* base = xyz + (size_t)b * N * 3;

  __shared__ int hist[NBUCKET];
  __shared__ unsigned cb[CAP];
  __shared__ int ci[CAP];
  __shared__ int s_nin, s_ncand, s_tb;
  __shared__ int s_wsum[KT / 64];
  __shared__ float s_cc[3];

  if (tid == 0) {
    const float* c = centers + (size_t)blk * 3;
    s_cc[0] = c[0]; s_cc[1] = c[1]; s_cc[2] = c[2];
    s_nin = 0; s_ncand = 0;
  }
  for (int i = tid; i < NBUCKET; i += KT) hist[i] = 0;
  __syncthreads();

  const float cx = s_cc[0], cy = s_cc[1], cz = s_cc[2];

  // pass 1: histogram of 10-bit float prefixes
  for (int n = tid; n < N; n += KT) {
    float d = sqdist(base[n * 3], base[n * 3 + 1], base[n * 3 + 2], cx, cy, cz);
    atomicAdd(&hist[__float_as_uint(d) >> 21], 1);
  }
  __syncthreads();

  // block scan over 1024 buckets (4 per thread) to find threshold bucket
  int h0[4];
  int loc = 0;
#pragma unroll
  for (int i = 0; i < 4; ++i) { h0[i] = hist[tid * 4 + i]; loc += h0[i]; }
  int lane = tid & 63, wid = tid >> 6;
  int scan = loc;
  for (int off = 1; off < 64; off <<= 1) {
    int o = __shfl_up(scan, off, 64);
    if (lane >= off) scan += o;
  }
  if (lane == 63) s_wsum[wid] = scan;
  __syncthreads();
  int woff = 0;
  for (int w = 0; w < wid; ++w) woff += s_wsum[w];
  int c0 = woff + scan - loc;  // count strictly below this thread's buckets
#pragma unroll
  for (int i = 0; i < 4; ++i) {
    int c1 = c0 + h0[i];
    if (c0 < K && c1 >= K) s_tb = tid * 4 + i;  // unique crossing bucket
    c0 = c1;
  }
  __syncthreads();
  const int tb = s_tb;
  const unsigned lo = (unsigned)tb << 21;
  const unsigned hi = (unsigned)(tb + 1) << 21;

  // pass 2: emit sure-ins, collect boundary candidates
  for (int n = tid; n < N; n += KT) {
    float x = base[n * 3], y = base[n * 3 + 1], z = base[n * 3 + 2];
    float d = sqdist(x, y, z, cx, cy, cz);
    unsigned bits = __float_as_uint(d);
    if (bits < lo) {
      int pos = atomicAdd(&s_nin, 1);
      float* p = patches + ((size_t)blk * K + pos) * 3;
      p[0] = __fsub_rn(x, cx); p[1] = __fsub_rn(y, cy); p[2] = __fsub_rn(z, cz);
    } else if (bits < hi) {
      int q = atomicAdd(&s_ncand, 1);
      if (q < CAP) { cb[q] = bits; ci[q] = n; }
    }
  }
  __syncthreads();

  // exact rank-select among boundary candidates: (bits, idx) lexicographic
  const int nin = s_nin;
  const int ncand = min(s_ncand, CAP);
  const int nsel = K - nin;
  for (int j = tid; j < ncand; j += KT) {
    unsigned bj = cb[j];
    int ij = ci[j];
    int rank = 0;
    for (int i2 = 0; i2 < ncand; ++i2) {
      unsigned bv = cb[i2];
      int iv = ci[i2];
      rank += (bv < bj || (bv == bj && iv < ij)) ? 1 : 0;
    }
    if (rank < nsel) {
      float x = base[ij * 3], y = base[ij * 3 + 1], z = base[ij * 3 + 2];
      float* p = patches + ((size_t)blk * K + nin + rank) * 3;
      p[0] = __fsub_rn(x, cx); p[1] = __fsub_rn(y, cy); p[2] = __fsub_rn(z, cz);
    }
  }
}

// ---------------------------------------------------------------- MLP ------
// One block per patch. h1/h2 staged in LDS, rows XOR-swizzled so the b128
// writes are conflict-light; reads are uniform-address broadcasts.
constexpr int MT = 128;

__global__ __launch_bounds__(MT) void mlp_kernel(
    const float* __restrict__ patches,
    const float* __restrict__ W1, const float* __restrict__ b1,
    const float* __restrict__ g1, const float* __restrict__ bt1,
    const float* __restrict__ W2, const float* __restrict__ b2,
    const float* __restrict__ g2, const float* __restrict__ bt2,
    const float* __restrict__ W3, const float* __restrict__ b3,
    const float* __restrict__ g3, const float* __restrict__ bt3,
    float* __restrict__ tokens) {
  const int pm = blockIdx.x;
  const int tid = threadIdx.x;
  __shared__ float xs[3][K];
  __shared__ float h1s[64 * K];
  __shared__ float h2s[128 * K];
  __shared__ float pms[2][EMB];

  const float* patch = patches + (size_t)pm * (K * 3);
  if (tid < 96) xs[tid % 3][tid / 3] = patch[tid];
  __syncthreads();

  const int cg = tid & 63;
  const int half = tid >> 6;
  const int pt0 = half * 16;
  const float rs = 1.0f / sqrtf(1.0f + 1e-5f);

  // L1: 3 -> 64
  {
    const int c = cg;
    const float w0 = W1[c], w1 = W1[64 + c], w2 = W1[128 + c];
    const float bb = b1[c];
    const float sc = g1[c] * rs, be = bt1[c];
    float o[16];
#pragma unroll
    for (int p = 0; p < 16; ++p) {
      int pt = pt0 + p;
      float a = xs[0][pt] * w0 + xs[1][pt] * w1 + xs[2][pt] * w2 + bb;
      o[p] = fmaxf(a * sc + be, 0.0f);
    }
    const int so = (c & 7) << 2;
#pragma unroll
    for (int p4 = 0; p4 < 16; p4 += 4) {
      *(float4*)&h1s[c * K + ((pt0 + p4) ^ so)] =
          make_float4(o[p4], o[p4 + 1], o[p4 + 2], o[p4 + 3]);
    }
  }
  __syncthreads();

  // L2: 64 -> 128, c-tile 2 x pt-tile 16
  {
    const int c = cg * 2;
    float acc0[16], acc1[16];
    const float bb0 = b2[c], bb1 = b2[c + 1];
#pragma unroll
    for (int p = 0; p < 16; ++p) { acc0[p] = bb0; acc1[p] = bb1; }
    for (int k = 0; k < 64; ++k) {
      const float2 w = *(const float2*)(W2 + k * 128 + c);
      const int so = (k & 7) << 2;
      float4 x0 = *(const float4*)&h1s[k * K + ((pt0 + 0) ^ so)];
      float4 x1 = *(const float4*)&h1s[k * K + ((pt0 + 4) ^ so)];
      float4 x2 = *(const float4*)&h1s[k * K + ((pt0 + 8) ^ so)];
      float4 x3 = *(const float4*)&h1s[k * K + ((pt0 + 12) ^ so)];
      float xv[16] = {x0.x, x0.y, x0.z, x0.w, x1.x, x1.y, x1.z, x1.w,
                      x2.x, x2.y, x2.z, x2.w, x3.x, x3.y, x3.z, x3.w};
#pragma unroll
      for (int p = 0; p < 16; ++p) {
        acc0[p] += xv[p] * w.x;
        acc1[p] += xv[p] * w.y;
      }
    }
    const float sc0 = g2[c] * rs, be0 = bt2[c];
    const float sc1 = g2[c + 1] * rs, be1 = bt2[c + 1];
    float o0[16], o1[16];
#pragma unroll
    for (int p = 0; p < 16; ++p) {
      o0[p] = fmaxf(acc0[p] * sc0 + be0, 0.0f);
      o1[p] = fmaxf(acc1[p] * sc1 + be1, 0.0f);
    }
    const int soa = (c & 7) << 2, sob = ((c + 1) & 7) << 2;
#pragma unroll
    for (int p4 = 0; p4 < 16; p4 += 4) {
      *(float4*)&h2s[c * K + ((pt0 + p4) ^ soa)] =
          make_float4(o0[p4], o0[p4 + 1], o0[p4 + 2], o0[p4 + 3]);
      *(float4*)&h2s[(c + 1) * K + ((pt0 + p4) ^ sob)] =
          make_float4(o1[p4], o1[p4 + 1], o1[p4 + 2], o1[p4 + 3]);
    }
  }
  __syncthreads();

  // L3: 128 -> 256, c-tile 4 x pt-tile 16, fused BN+ReLU+max over its pts
  {
    const int c = cg * 4;
    float acc[4][16];
#pragma unroll
    for (int i = 0; i < 4; ++i) {
      const float bb = b3[c + i];
#pragma unroll
      for (int p = 0; p < 16; ++p) acc[i][p] = bb;
    }
    for (int k = 0; k < 128; ++k) {
      const float4 w = *(const float4*)(W3 + (size_t)k * 256 + c);
      const int so = (k & 7) << 2;
      float4 x0 = *(const float4*)&h2s[k * K + ((pt0 + 0) ^ so)];
      float4 x1 = *(const float4*)&h2s[k * K + ((pt0 + 4) ^ so)];
      float4 x2 = *(const float4*)&h2s[k * K + ((pt0 + 8) ^ so)];
      float4 x3 = *(const float4*)&h2s[k * K + ((pt0 + 12) ^ so)];
      float xv[16] = {x0.x, x0.y, x0.z, x0.w, x1.x, x1.y, x1.z, x1.w,
                      x2.x, x2.y, x2.z, x2.w, x3.x, x3.y, x3.z, x3.w};
#pragma unroll
      for (int p = 0; p < 16; ++p) {
        acc[0][p] += xv[p] * w.x;
        acc[1][p] += xv[p] * w.y;
        acc[2][p] += xv[p] * w.z;
        acc[3][p] += xv[p] * w.w;
      }
    }
#pragma unroll
    for (int i = 0; i < 4; ++i) {
      const float sc = g3[c + i] * rs, be = bt3[c + i];
      float mx = 0.0f;  // ReLU outputs are >= 0, so 0 is a safe identity
#pragma unroll
      for (int p = 0; p < 16; ++p)
        mx = fmaxf(mx, fmaxf(acc[i][p] * sc + be, 0.0f));
      pms[half][c + i] = mx;
    }
  }
  __syncthreads();

  {
    const int c2 = tid * 2;
    float* to = tokens + (size_t)pm * EMB;
    to[c2] = fmaxf(pms[0][c2], pms[1][c2]);
    to[c2 + 1] = fmaxf(pms[0][c2 + 1], pms[1][c2 + 1]);
  }
}

// ------------------------------------------------------------- launcher ----
extern "C" void kernel_launch(void* const* d_in, const int* in_sizes, int n_in,
                              void* d_out, int out_size, void* d_ws,
                              size_t ws_size, hipStream_t stream) {
  const float* xyz = (const float*)d_in[0];
  const float* W1 = (const float*)d_in[1];
  const float* b1 = (const float*)d_in[2];
  const float* g1 = (const float*)d_in[3];
  const float* bt1 = (const float*)d_in[4];
  const float* W2 = (const float*)d_in[5];
  const float* b2 = (const float*)d_in[6];
  const float* g2 = (const float*)d_in[7];
  const float* bt2 = (const float*)d_in[8];
  const float* W3 = (const float*)d_in[9];
  const float* b3 = (const float*)d_in[10];
  const float* g3 = (const float*)d_in[11];
  const float* bt3 = (const float*)d_in[12];

  float* tokens = (float*)d_out;                       // (B,M,EMB)
  float* centers = tokens + (size_t)B * M * EMB;       // (B,M,3)
  float* patches = (float*)d_ws;                       // (B*M, K, 3)

  fps_kernel<<<B, FT, 0, stream>>>(xyz, centers);
  knn_kernel<<<B * M, KT, 0, stream>>>(xyz, centers, patches);
  mlp_kernel<<<B * M, MT, 0, stream>>>(patches, W1, b1, g1, bt1, W2, b2, g2,
                                       bt2, W3, b3, g3, bt3, tokens);
}

// Round 13
// 947.267 us; speedup vs baseline: 1.5479x; 1.0695x over previous
//
#include <hip/hip_runtime.h>

// Problem constants (fixed by setup_inputs)
constexpr int B   = 16;
constexpr int N   = 16384;
constexpr int M   = 256;   // n_centers
constexpr int K   = 32;    // knn
constexpr int EMB = 256;

// Exact (non-contracted) squared distance in the reference's association
// order: ((dx*dx + dy*dy) + dz*dz). Must be bit-identical to XLA CPU so the
// FPS argmax / kNN top-k selections match.
__device__ __forceinline__ float sqdist(float px, float py, float pz,
                                        float cx, float cy, float cz) {
  float dx = __fsub_rn(px, cx);
  float dy = __fsub_rn(py, cy);
  float dz = __fsub_rn(pz, cz);
  return __fadd_rn(__fadd_rn(__fmul_rn(dx, dx), __fmul_rn(dy, dy)),
                   __fmul_rn(dz, dz));
}

// ---------------------------------------------------------------- FPS ------
// Consolidated model (r5-r12): per-iter cost ~ bytes-moved / 64B/cyc on the
// CU's memory pipes. Scalar LDS (r12: 5.8cyc/b32 wave-op) and scratch spill
// (r6-r9) both lose. v5: minimize bytes + issues.
//   - dist: 16 named floats/thread (the ONLY loop-carried bulk state;
//     allocator grants 48-52 VGPR at 1024thr, 16+working fits)
//   - coords: re-streamed each iter, BLOCKED layout (thread owns 16
//     consecutive pts) -> 12 x b128 loads (196KB/iter, dense, 4x fewer
//     issues than strided b32)
//   - zero bulk LDS; one barrier/iter (parity-double-buffered partials)
// ~3100cyc VMEM + overlapped VALU + ~400cyc tail ~= 1.3-1.5us/iter.
constexpr int FT = 1024;
constexpr int FW = FT / 64;       // 16 waves

#define FPS_REP16(X) X(0) X(1) X(2) X(3) X(4) X(5) X(6) X(7) X(8) X(9) \
  X(10) X(11) X(12) X(13) X(14) X(15)

__global__ __launch_bounds__(FT) void fps_kernel(
    const float* __restrict__ xyz, float* __restrict__ centers) {
  const int b = blockIdx.x;
  const int tid = threadIdx.x;
  const float* base = xyz + (size_t)b * N * 3;
  const float4* b4 = (const float4*)base;   // 16B-aligned (allocator)

#define FPS_DECL(i) float ds##i = __builtin_inff();
  FPS_REP16(FPS_DECL)
#undef FPS_DECL

  __shared__ float s_pv[2][FW];
  __shared__ int s_pn[2][FW];

  // deterministic start: carry = point 0
  float cx = base[0], cy = base[1], cz = base[2];

  const int f0 = tid * 12;   // first float4 of this thread's 16-pt block

  for (int it = 0; it < M; ++it) {
    if (tid == 0) {  // emit current carry (matches lax.scan semantics)
      float* co = centers + ((size_t)b * M + it) * 3;
      co[0] = cx; co[1] = cy; co[2] = cz;
    }
    const int p = it & 1;

    float bv = -1.0f;
    int bj = 0;

    // strict > : ascending j, first (lowest j -> lowest global idx) wins ties
#define FPS_UPD(dn, j, X, Y, Z) {                          \
    float dx = __fsub_rn((X), cx);                         \
    float dy = __fsub_rn((Y), cy);                         \
    float dz = __fsub_rn((Z), cz);                         \
    float dd = __fadd_rn(__fadd_rn(__fmul_rn(dx, dx),      \
                                   __fmul_rn(dy, dy)),     \
                         __fmul_rn(dz, dz));               \
    float nd = fminf(dn, dd);                              \
    dn = nd;                                               \
    bool g = nd > bv;                                      \
    bv = g ? nd : bv;                                      \
    bj = g ? (j) : bj; }

#define FPS_CHUNK(c, dA, dB, dC, dD) {                     \
    float4 qa = b4[f0 + (c) * 3 + 0];                      \
    float4 qb = b4[f0 + (c) * 3 + 1];                      \
    float4 qc = b4[f0 + (c) * 3 + 2];                      \
    FPS_UPD(dA, (c) * 4 + 0, qa.x, qa.y, qa.z)             \
    FPS_UPD(dB, (c) * 4 + 1, qa.w, qb.x, qb.y)             \
    FPS_UPD(dC, (c) * 4 + 2, qb.z, qb.w, qc.x)             \
    FPS_UPD(dD, (c) * 4 + 3, qc.y, qc.z, qc.w) }

    FPS_CHUNK(0, ds0, ds1, ds2, ds3)
    FPS_CHUNK(1, ds4, ds5, ds6, ds7)
    FPS_CHUNK(2, ds8, ds9, ds10, ds11)
    FPS_CHUNK(3, ds12, ds13, ds14, ds15)
#undef FPS_CHUNK
#undef FPS_UPD

    int bn = (tid << 4) + bj;   // global point index (blocked mapping)

    // wave-level argmax, tie -> lowest global index
#pragma unroll
    for (int mm = 32; mm >= 1; mm >>= 1) {
      float ov = __shfl_xor(bv, mm, 64);
      int on = __shfl_xor(bn, mm, 64);
      if (ov > bv || (ov == bv && on < bn)) { bv = ov; bn = on; }
    }
    if ((tid & 63) == 0) { s_pv[p][tid >> 6] = bv; s_pn[p][tid >> 6] = bn; }
    __syncthreads();

    // every thread reduces the 16 wave partials (broadcast LDS reads)
    float v = s_pv[p][0];
    int n = s_pn[p][0];
#pragma unroll
    for (int w = 1; w < FW; ++w) {
      float ov = s_pv[p][w];
      int on = s_pn[p][w];
      if (ov > v || (ov == v && on < n)) { v = ov; n = on; }
    }
    // broadcast-load next center (uniform address -> one L1 fetch)
    cx = base[(size_t)n * 3 + 0];
    cy = base[(size_t)n * 3 + 1];
    cz = base[(size_t)n * 3 + 2];
    // no second barrier: parity-double-buffered partials make it race-free
  }
}

// ---------------------------------------------------------------- kNN ------
// Bucket-select on float bit prefixes (monotone for d >= 0). Only the SET of
// 32 nearest matters (max-pool later), so slots are written in arbitrary
// order; boundary-bucket ties resolved exactly by (bits, index).
constexpr int KT = 256;
constexpr int CAP = 512;
constexpr int NBUCKET = 1024;

__global__ __launch_bounds__(KT) void knn_kernel(
    const float* __restrict__ xyz, const float* __restrict__ centers,
    float* __restrict__ patches) {
  const int blk = blockIdx.x;      // b*M + m
  const int b = blk >> 8;          // M == 256
  const int tid = threadIdx.x;
  const float* base = xyz + (size_t)b * N * 3;

  __shared__ int hist[NBUCKET];
  __shared__ unsigned cb[CAP];
  __shared__ int ci[CAP];
  __shared__ int s_nin, s_ncand, s_tb;
  __shared__ int s_wsum[KT / 64];
  __shared__ float s_cc[3];

  if (tid == 0) {
    const float* c = centers + (size_t)blk * 3;
    s_cc[0] = c[0]; s_cc[1] = c[1]; s_cc[2] = c[2];
    s_nin = 0; s_ncand = 0;
  }
  for (int i = tid; i < NBUCKET; i += KT) hist[i] = 0;
  __syncthreads();

  const float cx = s_cc[0], cy = s_cc[1], cz = s_cc[2];

  // pass 1: histogram of 10-bit float prefixes
  for (int n = tid; n < N; n += KT) {
    float d = sqdist(base[n * 3], base[n * 3 + 1], base[n * 3 + 2], cx, cy, cz);
    atomicAdd(&hist[__float_as_uint(d) >> 21], 1);
  }
  __syncthreads();

  // block scan over 1024 buckets (4 per thread) to find threshold bucket
  int h0[4];
  int loc = 0;
#pragma unroll
  for (int i = 0; i < 4; ++i) { h0[i] = hist[tid * 4 + i]; loc += h0[i]; }
  int lane = tid & 63, wid = tid >> 6;
  int scan = loc;
  for (int off = 1; off < 64; off <<= 1) {
    int o = __shfl_up(scan, off, 64);
    if (lane >= off) scan += o;
  }
  if (lane == 63) s_wsum[wid] = scan;
  __syncthreads();
  int woff = 0;
  for (int w = 0; w < wid; ++w) woff += s_wsum[w];
  int c0 = woff + scan - loc;  // count strictly below this thread's buckets
#pragma unroll
  for (int i = 0; i < 4; ++i) {
    int c1 = c0 + h0[i];
    if (c0 < K && c1 >= K) s_tb = tid * 4 + i;  // unique crossing bucket
    c0 = c1;
  }
  __syncthreads();
  const int tb = s_tb;
  const unsigned lo = (unsigned)tb << 21;
  const unsigned hi = (unsigned)(tb + 1) << 21;

  // pass 2: emit sure-ins, collect boundary candidates
  for (int n = tid; n < N; n += KT) {
    float x = base[n * 3], y = base[n * 3 + 1], z = base[n * 3 + 2];
    float d = sqdist(x, y, z, cx, cy, cz);
    unsigned bits = __float_as_uint(d);
    if (bits < lo) {
      int pos = atomicAdd(&s_nin, 1);
      float* p = patches + ((size_t)blk * K + pos) * 3;
      p[0] = __fsub_rn(x, cx); p[1] = __fsub_rn(y, cy); p[2] = __fsub_rn(z, cz);
    } else if (bits < hi) {
      int q = atomicAdd(&s_ncand, 1);
      if (q < CAP) { cb[q] = bits; ci[q] = n; }
    }
  }
  __syncthreads();

  // exact rank-select among boundary candidates: (bits, idx) lexicographic
  const int nin = s_nin;
  const int ncand = min(s_ncand, CAP);
  const int nsel = K - nin;
  for (int j = tid; j < ncand; j += KT) {
    unsigned bj = cb[j];
    int ij = ci[j];
    int rank = 0;
    for (int i2 = 0; i2 < ncand; ++i2) {
      unsigned bv = cb[i2];
      int iv = ci[i2];
      rank += (bv < bj || (bv == bj && iv < ij)) ? 1 : 0;
    }
    if (rank < nsel) {
      float x = base[ij * 3], y = base[ij * 3 + 1], z = base[ij * 3 + 2];
      float* p = patches + ((size_t)blk * K + nin + rank) * 3;
      p[0] = __fsub_rn(x, cx); p[1] = __fsub_rn(y, cy); p[2] = __fsub_rn(z, cz);
    }
  }
}

// ---------------------------------------------------------------- MLP ------
// One block per patch. h1/h2 staged in LDS, rows XOR-swizzled so the b128
// writes are conflict-light; reads are uniform-address broadcasts.
constexpr int MT = 128;

__global__ __launch_bounds__(MT) void mlp_kernel(
    const float* __restrict__ patches,
    const float* __restrict__ W1, const float* __restrict__ b1,
    const float* __restrict__ g1, const float* __restrict__ bt1,
    const float* __restrict__ W2, const float* __restrict__ b2,
    const float* __restrict__ g2, const float* __restrict__ bt2,
    const float* __restrict__ W3, const float* __restrict__ b3,
    const float* __restrict__ g3, const float* __restrict__ bt3,
    float* __restrict__ tokens) {
  const int pm = blockIdx.x;
  const int tid = threadIdx.x;
  __shared__ float xs[3][K];
  __shared__ float h1s[64 * K];
  __shared__ float h2s[128 * K];
  __shared__ float pms[2][EMB];

  const float* patch = patches + (size_t)pm * (K * 3);
  if (tid < 96) xs[tid % 3][tid / 3] = patch[tid];
  __syncthreads();

  const int cg = tid & 63;
  const int half = tid >> 6;
  const int pt0 = half * 16;
  const float rs = 1.0f / sqrtf(1.0f + 1e-5f);

  // L1: 3 -> 64
  {
    const int c = cg;
    const float w0 = W1[c], w1 = W1[64 + c], w2 = W1[128 + c];
    const float bb = b1[c];
    const float sc = g1[c] * rs, be = bt1[c];
    float o[16];
#pragma unroll
    for (int p = 0; p < 16; ++p) {
      int pt = pt0 + p;
      float a = xs[0][pt] * w0 + xs[1][pt] * w1 + xs[2][pt] * w2 + bb;
      o[p] = fmaxf(a * sc + be, 0.0f);
    }
    const int so = (c & 7) << 2;
#pragma unroll
    for (int p4 = 0; p4 < 16; p4 += 4) {
      *(float4*)&h1s[c * K + ((pt0 + p4) ^ so)] =
          make_float4(o[p4], o[p4 + 1], o[p4 + 2], o[p4 + 3]);
    }
  }
  __syncthreads();

  // L2: 64 -> 128, c-tile 2 x pt-tile 16
  {
    const int c = cg * 2;
    float acc0[16], acc1[16];
    const float bb0 = b2[c], bb1 = b2[c + 1];
#pragma unroll
    for (int p = 0; p < 16; ++p) { acc0[p] = bb0; acc1[p] = bb1; }
    for (int k = 0; k < 64; ++k) {
      const float2 w = *(const float2*)(W2 + k * 128 + c);
      const int so = (k & 7) << 2;
      float4 x0 = *(const float4*)&h1s[k * K + ((pt0 + 0) ^ so)];
      float4 x1 = *(const float4*)&h1s[k * K + ((pt0 + 4) ^ so)];
      float4 x2 = *(const float4*)&h1s[k * K + ((pt0 + 8) ^ so)];
      float4 x3 = *(const float4*)&h1s[k * K + ((pt0 + 12) ^ so)];
      float xv[16] = {x0.x, x0.y, x0.z, x0.w, x1.x, x1.y, x1.z, x1.w,
                      x2.x, x2.y, x2.z, x2.w, x3.x, x3.y, x3.z, x3.w};
#pragma unroll
      for (int p = 0; p < 16; ++p) {
        acc0[p] += xv[p] * w.x;
        acc1[p] += xv[p] * w.y;
      }
    }
    const float sc0 = g2[c] * rs, be0 = bt2[c];
    const float sc1 = g2[c + 1] * rs, be1 = bt2[c + 1];
    float o0[16], o1[16];
#pragma unroll
    for (int p = 0; p < 16; ++p) {
      o0[p] = fmaxf(acc0[p] * sc0 + be0, 0.0f);
      o1[p] = fmaxf(acc1[p] * sc1 + be1, 0.0f);
    }
    const int soa = (c & 7) << 2, sob = ((c + 1) & 7) << 2;
#pragma unroll
    for (int p4 = 0; p4 < 16; p4 += 4) {
      *(float4*)&h2s[c * K + ((pt0 + p4) ^ soa)] =
          make_float4(o0[p4], o0[p4 + 1], o0[p4 + 2], o0[p4 + 3]);
      *(float4*)&h2s[(c + 1) * K + ((pt0 + p4) ^ sob)] =
          make_float4(o1[p4], o1[p4 + 1], o1[p4 + 2], o1[p4 + 3]);
    }
  }
  __syncthreads();

  // L3: 128 -> 256, c-tile 4 x pt-tile 16, fused BN+ReLU+max over its pts
  {
    const int c = cg * 4;
    float acc[4][16];
#pragma unroll
    for (int i = 0; i < 4; ++i) {
      const float bb = b3[c + i];
#pragma unroll
      for (int p = 0; p < 16; ++p) acc[i][p] = bb;
    }
    for (int k = 0; k < 128; ++k) {
      const float4 w = *(const float4*)(W3 + (size_t)k * 256 + c);
      const int so = (k & 7) << 2;
      float4 x0 = *(const float4*)&h2s[k * K + ((pt0 + 0) ^ so)];
      float4 x1 = *(const float4*)&h2s[k * K + ((pt0 + 4) ^ so)];
      float4 x2 = *(const float4*)&h2s[k * K + ((pt0 + 8) ^ so)];
      float4 x3 = *(const float4*)&h2s[k * K + ((pt0 + 12) ^ so)];
      float xv[16] = {x0.x, x0.y, x0.z, x0.w, x1.x, x1.y, x1.z, x1.w,
                      x2.x, x2.y, x2.z, x2.w, x3.x, x3.y, x3.z, x3.w};
#pragma unroll
      for (int p = 0; p < 16; ++p) {
        acc[0][p] += xv[p] * w.x;
        acc[1][p] += xv[p] * w.y;
        acc[2][p] += xv[p] * w.z;
        acc[3][p] += xv[p] * w.w;
      }
    }
#pragma unroll
    for (int i = 0; i < 4; ++i) {
      const float sc = g3[c + i] * rs, be = bt3[c + i];
      float mx = 0.0f;  // ReLU outputs are >= 0, so 0 is a safe identity
#pragma unroll
      for (int p = 0; p < 16; ++p)
        mx = fmaxf(mx, fmaxf(acc[i][p] * sc + be, 0.0f));
      pms[half][c + i] = mx;
    }
  }
  __syncthreads();

  {
    const int c2 = tid * 2;
    float* to = tokens + (size_t)pm * EMB;
    to[c2] = fmaxf(pms[0][c2], pms[1][c2]);
    to[c2 + 1] = fmaxf(pms[0][c2 + 1], pms[1][c2 + 1]);
  }
}

// ------------------------------------------------------------- launcher ----
extern "C" void kernel_launch(void* const* d_in, const int* in_sizes, int n_in,
                              void* d_out, int out_size, void* d_ws,
                              size_t ws_size, hipStream_t stream) {
  const float* xyz = (const float*)d_in[0];
  const float* W1 = (const float*)d_in[1];
  const float* b1 = (const float*)d_in[2];
  const float* g1 = (const float*)d_in[3];
  const float* bt1 = (const float*)d_in[4];
  const float* W2 = (const float*)d_in[5];
  const float* b2 = (const float*)d_in[6];
  const float* g2 = (const float*)d_in[7];
  const float* bt2 = (const float*)d_in[8];
  const float* W3 = (const float*)d_in[9];
  const float* b3 = (const float*)d_in[10];
  const float* g3 = (const float*)d_in[11];
  const float* bt3 = (const float*)d_in[12];

  float* tokens = (float*)d_out;                       // (B,M,EMB)
  float* centers = tokens + (size_t)B * M * EMB;       // (B,M,3)
  float* patches = (float*)d_ws;                       // (B*M, K, 3)

  fps_kernel<<<B, FT, 0, stream>>>(xyz, centers);
  knn_kernel<<<B * M, KT, 0, stream>>>(xyz, centers, patches);
  mlp_kernel<<<B * M, MT, 0, stream>>>(patches, W1, b1, g1, bt1, W2, b2, g2,
                                       bt2, W3, b3, g3, bt3, tokens);
}